// Round 5
// baseline (228.116 us; speedup 1.0000x reference)
//
#include <hip/hip_runtime.h>
#include <math.h>

#define N_NODES 8192
#define N_CLAIM 128
#define HIDDEN  300
#define KEEP    5735   // N - int(0.3*N) = 8192 - 2457
#define KC      50
#define SHCP    132    // padded LDS stride for transposed Hc chunk

// ---------------- score (+prep folded): 4 nodes/wave, k-paired float2 LDS ----------------
// score = 0.5*(He@W1) + 0.5*(-log( softmax(He@Hc^T) @ rowsum(Hc) + 1e-10 ))
// Also zeroes the completion counter used by step1_select.
__global__ __launch_bounds__(512) void score_prep_kernel(
    const float* __restrict__ He, const float* __restrict__ Hc,
    const float* __restrict__ W1, float* __restrict__ score_out,
    unsigned int* __restrict__ done) {
  if (blockIdx.x == 0 && threadIdx.x == 0) done[0] = 0u;

  __shared__ float she[32][HIDDEN];    // 38.4 KB
  __shared__ float shc[KC][SHCP];      // 26.4 KB (padded: stride 132 breaks bank conflicts)
  const int tid  = threadIdx.x;
  const int wave = tid >> 6, lane = tid & 63;
  const int nb   = blockIdx.x * 32;

  {  // stage 32 contiguous He rows (float4)
    const float4* src4 = (const float4*)(He + (size_t)nb * HIDDEN);
    float4* dst4 = (float4*)&she[0][0];
    for (int i = tid; i < 32 * HIDDEN / 4; i += 512) dst4[i] = src4[i];
  }

  float a[4][2] = {{0.f,0.f},{0.f,0.f},{0.f,0.f},{0.f,0.f}};
  float sA = 0.f, sB = 0.f;            // per-lane claim sums (scl for claims 2l,2l+1)
  for (int k0 = 0; k0 < HIDDEN; k0 += KC) {
    __syncthreads();
    // stage Hc chunk transposed: shc[k][j] = Hc[j][k0+k]
    for (int idx = tid; idx < N_CLAIM * (KC / 2); idx += 512) {
      int j  = idx / (KC / 2);
      int kk = idx - j * (KC / 2);
      float2 v = *(const float2*)(Hc + j * HIDDEN + k0 + 2 * kk);
      shc[2 * kk][j]     = v.x;
      shc[2 * kk + 1][j] = v.y;
    }
    __syncthreads();
    #pragma unroll 5
    for (int k = 0; k < KC; k += 2) {
      float2 ca = ((const float2*)&shc[k][0])[lane];       // claims 2l,2l+1 @ k
      float2 cb = ((const float2*)&shc[k + 1][0])[lane];   // claims 2l,2l+1 @ k+1
      sA += ca.x + cb.x;
      sB += ca.y + cb.y;
      #pragma unroll
      for (int n = 0; n < 4; ++n) {
        float2 h2v = ((const float2*)&she[wave * 4 + n][0])[(k0 + k) >> 1];  // broadcast
        a[n][0] = fmaf(h2v.x, ca.x, fmaf(h2v.y, cb.x, a[n][0]));
        a[n][1] = fmaf(h2v.x, ca.y, fmaf(h2v.y, cb.y, a[n][1]));
      }
    }
  }

  float res[4];
  #pragma unroll
  for (int n = 0; n < 4; ++n) {
    float m = fmaxf(a[n][0], a[n][1]);
    #pragma unroll
    for (int s = 32; s; s >>= 1) m = fmaxf(m, __shfl_xor(m, s));
    float e0 = expf(a[n][0] - m), e1 = expf(a[n][1] - m);
    float den = e0 + e1, num = e0 * sA + e1 * sB;
    #pragma unroll
    for (int s = 32; s; s >>= 1) { den += __shfl_xor(den, s); num += __shfl_xor(num, s); }
    float s1 = 0.f;
    for (int k = lane; k < HIDDEN; k += 64) s1 = fmaf(she[wave * 4 + n][k], W1[k], s1);
    #pragma unroll
    for (int s = 32; s; s >>= 1) s1 += __shfl_xor(s1, s);
    res[n] = 0.5f * s1 + 0.5f * (-logf(num / den + 1e-10f));
  }
  if (lane == 0) {
    int n0 = nb + wave * 4;
    #pragma unroll
    for (int n = 0; n < 4; ++n) score_out[n0 + n] = res[n];
  }
}

// ---------------- helpers ----------------
__device__ inline float gru_update(float acc, float hi,
                                   float Wz, float Uz, float Wr, float Ur,
                                   float Wh, float Uh) {
  float z  = 1.f / (1.f + expf(-(acc * Wz + hi * Uz)));
  float r  = 1.f / (1.f + expf(-(acc * Wr + hi * Ur)));
  float ht = tanhf(acc * Wh + (r * hi) * Uh);
  return (1.f - z) * hi + z * ht;
}

__device__ inline unsigned int mono_key(float f) {
  unsigned int u = __float_as_uint(f);
  return (u & 0x80000000u) ? ~u : (u | 0x80000000u);
}

// exclusive scan over 256 threads (4 waves)
__device__ inline unsigned int block_excl_scan_256(unsigned int v, unsigned int* wsum,
                                                   int wave, int lane, int tid) {
  unsigned int sc = v;
  #pragma unroll
  for (int off = 1; off < 64; off <<= 1) {
    unsigned int o = __shfl_up(sc, off);
    if (lane >= off) sc += o;
  }
  __syncthreads();
  if (lane == 63) wsum[wave] = sc;
  __syncthreads();
  if (tid == 0) {
    unsigned int run = 0;
    for (int w = 0; w < 4; ++w) { unsigned int t = wsum[w]; wsum[w] = run; run += t; }
  }
  __syncthreads();
  return wsum[wave] + sc - v;
}

// cooperative exact full-row dot, 256 threads (rescue path only)
__device__ inline float block_dot_256(const float* __restrict__ adjrow,
                                      const float* __restrict__ hvec,
                                      float* wred, int tid, int wave, int lane) {
  const float4* a4 = (const float4*)adjrow;
  const float4* h4 = (const float4*)hvec;
  float acc = 0.f;
  #pragma unroll
  for (int it = 0; it < 8; ++it) {
    int idx = tid + it * 256;
    float4 a = a4[idx], h = h4[idx];
    acc = fmaf(a.x, h.x, fmaf(a.y, h.y, fmaf(a.z, h.z, fmaf(a.w, h.w, acc))));
  }
  #pragma unroll
  for (int s = 32; s; s >>= 1) acc += __shfl_xor(acc, s);
  if (lane == 0) wred[wave] = acc;
  __syncthreads();
  if (tid == 0) { float t = 0.f; for (int w = 0; w < 4; ++w) t += wred[w]; wred[0] = t; }
  __syncthreads();
  float r = wred[0];
  __syncthreads();
  return r;
}

// ---------------- step1 matvec + (last block) refine steps 2/3 + exact stable select ----------------
__global__ __launch_bounds__(256) void step1_select_kernel(
    const float* __restrict__ adj, const float* __restrict__ h0,
    float* __restrict__ h1, float* __restrict__ a1, float* __restrict__ rsum,
    float* __restrict__ h2g, float* __restrict__ a2g, unsigned int* __restrict__ keyg,
    unsigned int* __restrict__ done,
    float* __restrict__ mask_out, int* __restrict__ keep_idx,
    const float* __restrict__ pWz, const float* __restrict__ pUz,
    const float* __restrict__ pWr, const float* __restrict__ pUr,
    const float* __restrict__ pWh, const float* __restrict__ pUh) {
  __shared__ unsigned int s_old;
  __shared__ unsigned int hist[256];
  __shared__ unsigned int rbits[256];
  __shared__ unsigned int wsum[4];
  __shared__ float wred[4];
  __shared__ int s_same, s_eqc, s_nresc;
  __shared__ unsigned int sh_b, sh_newr, sh_prefix, sh_r;

  const int tid = threadIdx.x;
  const int wave = tid >> 6, lane = tid & 63;
  const float Wz = pWz[0], Uz = pUz[0], Wr = pWr[0], Ur = pUr[0];
  const float Wh = pWh[0], Uh = pUh[0];

  // ======== phase 0: GGNN step 1 matvec + rowsum (4 rows per block) ========
  {
    const int row = blockIdx.x * 4 + wave;
    const float4* __restrict__ a4 = (const float4*)(adj + (size_t)row * N_NODES);
    const float4* __restrict__ h4 = (const float4*)h0;
    float acc = 0.f, rs = 0.f;
    #pragma unroll 8
    for (int it = 0; it < N_NODES / 256; ++it) {
      float4 a = a4[it * 64 + lane];
      float4 h = h4[it * 64 + lane];
      acc = fmaf(a.x, h.x, acc); acc = fmaf(a.y, h.y, acc);
      acc = fmaf(a.z, h.z, acc); acc = fmaf(a.w, h.w, acc);
      rs += (a.x + a.y) + (a.z + a.w);
    }
    #pragma unroll
    for (int s = 32; s; s >>= 1) { acc += __shfl_xor(acc, s); rs += __shfl_xor(rs, s); }
    if (lane == 0) {
      a1[row] = acc;
      rsum[row] = rs;
      h1[row] = gru_update(acc, h0[row], Wz, Uz, Wr, Ur, Wh, Uh);
    }
  }

  // ======== completion protocol: last-finishing block becomes the selector ========
  __syncthreads();                       // all waves' global writes issued & drained
  if (tid == 0) {
    __threadfence();                     // device-scope release (L2 writeback)
    s_old = atomicAdd(done, 1u);
  }
  __syncthreads();
  if (s_old != (unsigned)(N_NODES / 4 - 1)) return;   // 2047
  __threadfence();                       // acquire side

  const int base = tid * 32;             // 32 rows/keys per thread

  // ======== phase A: GGNN step 2 (certified fast paths) ========
  if (tid == 0) { s_same = 1; s_eqc = 1; s_nresc = 0; }
  __syncthreads();
  const float c0 = h1[0];
  {
    const float4* hc4 = (const float4*)h1;
    const float4* hp4 = (const float4*)h0;
    int same = 1, eqc = 1;
    for (int i = tid; i < N_NODES / 4; i += 256) {
      float4 x = hc4[i], y = hp4[i];
      same &= (x.x == y.x) & (x.y == y.y) & (x.z == y.z) & (x.w == y.w);
      eqc  &= (x.x == c0) & (x.y == c0) & (x.z == c0) & (x.w == c0);
    }
    if (!same) atomicAnd(&s_same, 0);
    if (!eqc)  atomicAnd(&s_eqc, 0);
  }
  __syncthreads();
  {
    unsigned int myresc = 0u;
    if (s_same) {
      for (int i = 0; i < 32; ++i) {
        int r = base + i;
        float acc = a1[r];               // adj@h1 == adj@h0 bitwise
        a2g[r] = acc;
        h2g[r] = gru_update(acc, h1[r], Wz, Uz, Wr, Ur, Wh, Uh);
      }
    } else if (s_eqc) {
      for (int i = 0; i < 32; ++i) {
        int r = base + i;
        float acc = c0 * rsum[r];
        a2g[r] = acc;
        float zarg = acc * Wz + c0 * Uz;
        float wt   = acc * Wh;
        if (zarg <= -200.f) h2g[r] = c0;                        // z==0 exactly
        else if (zarg >= 200.f && fabsf(wt) - fabsf(c0 * Uh) >= 30.f)
          h2g[r] = copysignf(1.f, wt);                          // z==1, tanh saturated
        else myresc |= (1u << i);
      }
    } else {
      myresc = 0xFFFFFFFFu;
    }
    rbits[tid] = myresc;
    if (myresc) atomicAdd(&s_nresc, __popc(myresc));
  }
  __syncthreads();
  if (s_nresc > 0) {                     // exact rescue (never fires when certs hold)
    for (int w = 0; w < 256; ++w) {
      unsigned int bits = rbits[w];
      while (bits) {
        int b = __ffs(bits) - 1; bits &= bits - 1;
        int i = w * 32 + b;
        float acc = block_dot_256(adj + (size_t)i * N_NODES, h1, wred, tid, wave, lane);
        if (tid == 0) {
          a2g[i] = acc;
          h2g[i] = gru_update(acc, h1[i], Wz, Uz, Wr, Ur, Wh, Uh);
        }
      }
    }
  }
  __syncthreads();

  // ======== phase B: GGNN step 3 -> monotone keys ========
  if (tid == 0) { s_same = 1; s_eqc = 1; s_nresc = 0; }
  __syncthreads();
  const float c1 = h2g[0];
  {
    const float4* hc4 = (const float4*)h2g;
    const float4* hp4 = (const float4*)h1;
    int same = 1, eqc = 1;
    for (int i = tid; i < N_NODES / 4; i += 256) {
      float4 x = hc4[i], y = hp4[i];
      same &= (x.x == y.x) & (x.y == y.y) & (x.z == y.z) & (x.w == y.w);
      eqc  &= (x.x == c1) & (x.y == c1) & (x.z == c1) & (x.w == c1);
    }
    if (!same) atomicAnd(&s_same, 0);
    if (!eqc)  atomicAnd(&s_eqc, 0);
  }
  __syncthreads();
  {
    unsigned int myresc = 0u;
    if (s_same) {
      for (int i = 0; i < 32; ++i) {
        int r = base + i;
        keyg[r] = mono_key(gru_update(a2g[r], h2g[r], Wz, Uz, Wr, Ur, Wh, Uh));
      }
    } else if (s_eqc) {
      for (int i = 0; i < 32; ++i) {
        int r = base + i;
        float acc = c1 * rsum[r];
        float zarg = acc * Wz + c1 * Uz;
        float wt   = acc * Wh;
        if (zarg <= -200.f) keyg[r] = mono_key(c1);
        else if (zarg >= 200.f && fabsf(wt) - fabsf(c1 * Uh) >= 30.f)
          keyg[r] = mono_key(copysignf(1.f, wt));
        else myresc |= (1u << i);
      }
    } else {
      myresc = 0xFFFFFFFFu;
    }
    rbits[tid] = myresc;
    if (myresc) atomicAdd(&s_nresc, __popc(myresc));
  }
  __syncthreads();
  if (s_nresc > 0) {
    for (int w = 0; w < 256; ++w) {
      unsigned int bits = rbits[w];
      while (bits) {
        int b = __ffs(bits) - 1; bits &= bits - 1;
        int i = w * 32 + b;
        float acc = block_dot_256(adj + (size_t)i * N_NODES, h2g, wred, tid, wave, lane);
        if (tid == 0)
          keyg[i] = mono_key(gru_update(acc, h2g[i], Wz, Uz, Wr, Ur, Wh, Uh));
      }
    }
  }
  __syncthreads();

  // ======== phase C: exact stable top-KEEP radix select ========
  unsigned int kv[32];
  #pragma unroll
  for (int q = 0; q < 8; ++q) {
    uint4 t = ((const uint4*)keyg)[tid * 8 + q];
    kv[q * 4 + 0] = t.x; kv[q * 4 + 1] = t.y; kv[q * 4 + 2] = t.z; kv[q * 4 + 3] = t.w;
  }
  if (tid == 0) { sh_prefix = 0u; sh_r = KEEP; }
  __syncthreads();

  for (int pass = 0; pass < 4; ++pass) {
    const int shift = 24 - pass * 8;
    hist[tid] = 0u;
    __syncthreads();
    const unsigned int pref = sh_prefix;
    const unsigned int r    = sh_r;
    #pragma unroll
    for (int i = 0; i < 32; ++i) {
      unsigned int k = kv[i];
      bool match = (pass == 0) || ((k >> (shift + 8)) == pref);
      unsigned int d = match ? ((k >> shift) & 255u) : 256u;
      unsigned long long m = ~0ull;
      #pragma unroll
      for (int b = 0; b < 9; ++b) {
        unsigned long long bal = __ballot((d >> b) & 1u);
        m &= ((d >> b) & 1u) ? bal : ~bal;
      }
      int leader = __ffsll((unsigned long long)m) - 1;
      if (lane == leader && d < 256u)
        atomicAdd(&hist[d], (unsigned int)__popcll(m));
    }
    __syncthreads();
    if (wave == 0) {
      unsigned int t0 = hist[lane * 4], t1 = hist[lane * 4 + 1];
      unsigned int t2 = hist[lane * 4 + 2], t3 = hist[lane * 4 + 3];
      unsigned int tot = t0 + t1 + t2 + t3;
      unsigned int sc = tot;
      #pragma unroll
      for (int off = 1; off < 64; off <<= 1) {
        unsigned int o = __shfl_up(sc, off);
        if (lane >= off) sc += o;
      }
      unsigned int e = sc - tot;
      unsigned int p0 = e + t0, p1 = p0 + t1, p2 = p1 + t2, p3 = p2 + t3;
      if (r > e  && r <= p0) { sh_b = lane * 4;     sh_newr = r - e;  }
      if (r > p0 && r <= p1) { sh_b = lane * 4 + 1; sh_newr = r - p0; }
      if (r > p1 && r <= p2) { sh_b = lane * 4 + 2; sh_newr = r - p1; }
      if (r > p2 && r <= p3) { sh_b = lane * 4 + 3; sh_newr = r - p2; }
    }
    __syncthreads();
    if (tid == 0) { sh_prefix = (pref << 8) | sh_b; sh_r = sh_newr; }
    __syncthreads();
  }
  const unsigned int Kk = sh_prefix;   // cutoff key (KEEP-th smallest)
  const unsigned int tk = sh_r;        // # of ==Kk elements kept (lowest indices first)

  unsigned int eqc = 0;
  #pragma unroll
  for (int i = 0; i < 32; ++i) eqc += (kv[i] == Kk) ? 1u : 0u;
  const unsigned int eqbase = block_excl_scan_256(eqc, wsum, wave, lane, tid);

  unsigned int runeq = eqbase, kc = 0;
  #pragma unroll
  for (int i = 0; i < 32; ++i) {
    unsigned int k = kv[i];
    bool kp;
    if (k == Kk) { kp = (runeq < tk); ++runeq; } else kp = (k < Kk);
    kc += kp ? 1u : 0u;
  }
  unsigned int pos = block_excl_scan_256(kc, wsum, wave, lane, tid);

  runeq = eqbase;
  #pragma unroll
  for (int i = 0; i < 32; ++i) {
    unsigned int k = kv[i];
    bool kp;
    if (k == Kk) { kp = (runeq < tk); ++runeq; } else kp = (k < Kk);
    mask_out[base + i] = kp ? 1.0f : 0.0f;
    if (kp) keep_idx[pos++] = base + i;
  }
}

// ---------------- gather kept rows (float4: rows are 75 aligned float4) ----------------
__global__ __launch_bounds__(256) void gather_kernel(
    const float* __restrict__ He, const int* __restrict__ keep_idx,
    float* __restrict__ out) {
  int t = blockIdx.x * 256 + threadIdx.x;
  if (t >= KEEP * (HIDDEN / 4)) return;
  int p = t / (HIDDEN / 4);
  int c = t - p * (HIDDEN / 4);
  const float4* src = (const float4*)(He + (size_t)keep_idx[p] * HIDDEN);
  ((float4*)out)[t] = src[c];
}

extern "C" void kernel_launch(void* const* d_in, const int* in_sizes, int n_in,
                              void* d_out, int out_size, void* d_ws, size_t ws_size,
                              hipStream_t stream) {
  const float* He  = (const float*)d_in[0];
  const float* Hc  = (const float*)d_in[1];
  const float* adj = (const float*)d_in[2];
  const float* W1  = (const float*)d_in[3];
  const float* Wz  = (const float*)d_in[4];
  const float* Uz  = (const float*)d_in[5];
  const float* Wr  = (const float*)d_in[6];
  const float* Ur  = (const float*)d_in[7];
  const float* Wh  = (const float*)d_in[8];
  const float* Uh  = (const float*)d_in[9];
  float* out = (float*)d_out;

  float* ws   = (float*)d_ws;
  float* h0   = ws;                          // [8192]
  float* h1   = ws + 1 * N_NODES;
  float* a1   = ws + 2 * N_NODES;
  float* rsum = ws + 3 * N_NODES;
  float* h2g  = ws + 4 * N_NODES;
  float* a2g  = ws + 5 * N_NODES;
  unsigned int* keyg = (unsigned int*)(ws + 6 * N_NODES);
  int* keep_idx      = (int*)(ws + 7 * N_NODES);
  unsigned int* done = (unsigned int*)(ws + 8 * N_NODES);

  float* mask_out = out + (size_t)KEEP * HIDDEN;

  score_prep_kernel  <<<N_NODES / 32, 512, 0, stream>>>(He, Hc, W1, h0, done);
  step1_select_kernel<<<N_NODES / 4, 256, 0, stream>>>(adj, h0, h1, a1, rsum,
                                                       h2g, a2g, keyg, done,
                                                       mask_out, keep_idx,
                                                       Wz, Uz, Wr, Ur, Wh, Uh);
  gather_kernel      <<<(KEEP * (HIDDEN / 4) + 255) / 256, 256, 0, stream>>>(He, keep_idx, out);
}

// Round 6
// 127.691 us; speedup vs baseline: 1.7865x; 1.7865x over previous
//
#include <hip/hip_runtime.h>
#include <math.h>

#define N_NODES 8192
#define N_CLAIM 128
#define HIDDEN  300
#define KEEP    5735   // N - int(0.3*N) = 8192 - 2457
#define KC      50
#define SHCP    132    // padded LDS stride for transposed Hc chunk

// ---------------- score (+prep folded): 4 nodes/wave, k-paired float2 LDS ----------------
// score = 0.5*(He@W1) + 0.5*(-log( softmax(He@Hc^T) @ rowsum(Hc) + 1e-10 ))
__global__ __launch_bounds__(512) void score_prep_kernel(
    const float* __restrict__ He, const float* __restrict__ Hc,
    const float* __restrict__ W1, float* __restrict__ score_out) {
  __shared__ float she[32][HIDDEN];    // 38.4 KB
  __shared__ float shc[KC][SHCP];      // 26.4 KB (padded stride breaks bank conflicts)
  const int tid  = threadIdx.x;
  const int wave = tid >> 6, lane = tid & 63;
  const int nb   = blockIdx.x * 32;

  {  // stage 32 contiguous He rows (float4)
    const float4* src4 = (const float4*)(He + (size_t)nb * HIDDEN);
    float4* dst4 = (float4*)&she[0][0];
    for (int i = tid; i < 32 * HIDDEN / 4; i += 512) dst4[i] = src4[i];
  }

  float a[4][2] = {{0.f,0.f},{0.f,0.f},{0.f,0.f},{0.f,0.f}};
  float sA = 0.f, sB = 0.f;            // per-lane claim sums (scl for claims 2l,2l+1)
  for (int k0 = 0; k0 < HIDDEN; k0 += KC) {
    __syncthreads();
    // stage Hc chunk transposed: shc[k][j] = Hc[j][k0+k]
    for (int idx = tid; idx < N_CLAIM * (KC / 2); idx += 512) {
      int j  = idx / (KC / 2);
      int kk = idx - j * (KC / 2);
      float2 v = *(const float2*)(Hc + j * HIDDEN + k0 + 2 * kk);
      shc[2 * kk][j]     = v.x;
      shc[2 * kk + 1][j] = v.y;
    }
    __syncthreads();
    #pragma unroll 5
    for (int k = 0; k < KC; k += 2) {
      float2 ca = ((const float2*)&shc[k][0])[lane];       // claims 2l,2l+1 @ k
      float2 cb = ((const float2*)&shc[k + 1][0])[lane];   // claims 2l,2l+1 @ k+1
      sA += ca.x + cb.x;
      sB += ca.y + cb.y;
      #pragma unroll
      for (int n = 0; n < 4; ++n) {
        float2 h2v = ((const float2*)&she[wave * 4 + n][0])[(k0 + k) >> 1];  // broadcast
        a[n][0] = fmaf(h2v.x, ca.x, fmaf(h2v.y, cb.x, a[n][0]));
        a[n][1] = fmaf(h2v.x, ca.y, fmaf(h2v.y, cb.y, a[n][1]));
      }
    }
  }

  float res[4];
  #pragma unroll
  for (int n = 0; n < 4; ++n) {
    float m = fmaxf(a[n][0], a[n][1]);
    #pragma unroll
    for (int s = 32; s; s >>= 1) m = fmaxf(m, __shfl_xor(m, s));
    float e0 = expf(a[n][0] - m), e1 = expf(a[n][1] - m);
    float den = e0 + e1, num = e0 * sA + e1 * sB;
    #pragma unroll
    for (int s = 32; s; s >>= 1) { den += __shfl_xor(den, s); num += __shfl_xor(num, s); }
    float s1 = 0.f;
    for (int k = lane; k < HIDDEN; k += 64) s1 = fmaf(she[wave * 4 + n][k], W1[k], s1);
    #pragma unroll
    for (int s = 32; s; s >>= 1) s1 += __shfl_xor(s1, s);
    res[n] = 0.5f * s1 + 0.5f * (-logf(num / den + 1e-10f));
  }
  if (lane == 0) {
    int n0 = nb + wave * 4;
    #pragma unroll
    for (int n = 0; n < 4; ++n) score_out[n0 + n] = res[n];
  }
}

// ---------------- GRU epilogue ----------------
__device__ inline float gru_update(float acc, float hi,
                                   float Wz, float Uz, float Wr, float Ur,
                                   float Wh, float Uh) {
  float z  = 1.f / (1.f + expf(-(acc * Wz + hi * Uz)));
  float r  = 1.f / (1.f + expf(-(acc * Wr + hi * Ur)));
  float ht = tanhf(acc * Wh + (r * hi) * Uh);
  return (1.f - z) * hi + z * ht;
}

// ---------------- GGNN step 1: full matvec + rowsum in the same pass (STANDALONE) ----------------
__global__ __launch_bounds__(256) void ggnn_step1(
    const float* __restrict__ adj, const float* __restrict__ h_in,
    float* __restrict__ h_out, float* __restrict__ a_out,
    float* __restrict__ rowsum_out,
    const float* __restrict__ pWz, const float* __restrict__ pUz,
    const float* __restrict__ pWr, const float* __restrict__ pUr,
    const float* __restrict__ pWh, const float* __restrict__ pUh) {
  const int wave = threadIdx.x >> 6, lane = threadIdx.x & 63;
  const int row  = blockIdx.x * 4 + wave;
  const float4* __restrict__ a4 = (const float4*)(adj + (size_t)row * N_NODES);
  const float4* __restrict__ h4 = (const float4*)h_in;
  float acc = 0.f, rs = 0.f;
  #pragma unroll 8
  for (int it = 0; it < N_NODES / 256; ++it) {
    float4 a = a4[it * 64 + lane];
    float4 h = h4[it * 64 + lane];
    acc = fmaf(a.x, h.x, acc); acc = fmaf(a.y, h.y, acc);
    acc = fmaf(a.z, h.z, acc); acc = fmaf(a.w, h.w, acc);
    rs += (a.x + a.y) + (a.z + a.w);
  }
  #pragma unroll
  for (int s = 32; s; s >>= 1) { acc += __shfl_xor(acc, s); rs += __shfl_xor(rs, s); }
  if (lane == 0) {
    a_out[row] = acc;
    rowsum_out[row] = rs;
    h_out[row] = gru_update(acc, h_in[row], pWz[0], pUz[0], pWr[0], pUr[0], pWh[0], pUh[0]);
  }
}

// ---------------- fused: steps 2+3 (certified fast paths) + exact stable select ----------------
__device__ inline unsigned int block_excl_scan_1024(unsigned int v, unsigned int* wsum,
                                                    int wave, int lane, int tid) {
  unsigned int sc = v;
  #pragma unroll
  for (int off = 1; off < 64; off <<= 1) {
    unsigned int o = __shfl_up(sc, off);
    if (lane >= off) sc += o;
  }
  __syncthreads();
  if (lane == 63) wsum[wave] = sc;
  __syncthreads();
  if (tid == 0) {
    unsigned int run = 0;
    for (int w = 0; w < 16; ++w) { unsigned int t = wsum[w]; wsum[w] = run; run += t; }
  }
  __syncthreads();
  return wsum[wave] + sc - v;
}

// cooperative full-row dot (rescue path; exact fp32, never fires for certified data)
__device__ inline float block_dot_8192(const float* __restrict__ adjrow,
                                       const float4* __restrict__ h4,
                                       float* wred, int tid, int wave, int lane) {
  const float4* a4 = (const float4*)adjrow;
  float acc = 0.f;
  #pragma unroll
  for (int it = 0; it < 2; ++it) {
    int idx = tid + it * 1024;               // 2048 float4 per row
    float4 a = a4[idx]; float4 h = h4[idx];
    acc = fmaf(a.x, h.x, fmaf(a.y, h.y, fmaf(a.z, h.z, fmaf(a.w, h.w, acc))));
  }
  #pragma unroll
  for (int s = 32; s; s >>= 1) acc += __shfl_xor(acc, s);
  if (lane == 0) wred[wave] = acc;
  __syncthreads();
  if (tid == 0) { float t = 0.f; for (int w = 0; w < 16; ++w) t += wred[w]; wred[0] = t; }
  __syncthreads();
  float r = wred[0];
  __syncthreads();
  return r;
}

__global__ __launch_bounds__(1024) void fused_refine_select(
    const float* __restrict__ h0, const float* __restrict__ h1,
    const float* __restrict__ a1, const float* __restrict__ rsum,
    const float* __restrict__ adj,
    float* __restrict__ mask_out, int* __restrict__ keep_idx,
    const float* __restrict__ pWz, const float* __restrict__ pUz,
    const float* __restrict__ pWr, const float* __restrict__ pUr,
    const float* __restrict__ pWh, const float* __restrict__ pUh) {
  __shared__ float h2s[N_NODES];           // 32 KB
  __shared__ float a2s[N_NODES];           // 32 KB
  __shared__ unsigned int keyz[N_NODES];   // 32 KB
  __shared__ unsigned int hist[256];
  __shared__ unsigned int rbits[256];
  __shared__ unsigned int wsum[16];
  __shared__ float wred[16];
  __shared__ int s_same, s_eqc, s_nresc;
  __shared__ unsigned int sh_b, sh_newr, sh_prefix, sh_r;

  const int tid = threadIdx.x;
  const int wave = tid >> 6, lane = tid & 63;
  const int base = tid * 8;
  const float Wz = pWz[0], Uz = pUz[0], Wr = pWr[0], Ur = pUr[0];
  const float Wh = pWh[0], Uh = pUh[0];

  // ================= phase A: GGNN step 2 =================
  if (tid == 0) { s_same = 1; s_eqc = 1; s_nresc = 0; }
  if (tid < 256) rbits[tid] = 0u;
  __syncthreads();
  const float c0 = h1[0];
  {
    const float4* hc4 = (const float4*)h1;
    const float4* hp4 = (const float4*)h0;
    int same = 1, eqc = 1;
    for (int i = tid; i < N_NODES / 4; i += 1024) {
      float4 x = hc4[i], y = hp4[i];
      same &= (x.x == y.x) & (x.y == y.y) & (x.z == y.z) & (x.w == y.w);
      eqc  &= (x.x == c0) & (x.y == c0) & (x.z == c0) & (x.w == c0);
    }
    if (!same) atomicAnd(&s_same, 0);
    if (!eqc)  atomicAnd(&s_eqc, 0);
  }
  __syncthreads();
  {
    const int fsame = s_same, feqc = s_eqc;
    if (fsame) {
      for (int r = base; r < base + 8; ++r) {
        float acc = a1[r];                   // adj@h1 == adj@h0 bitwise
        a2s[r] = acc;
        h2s[r] = gru_update(acc, h1[r], Wz, Uz, Wr, Ur, Wh, Uh);
      }
    } else if (feqc) {
      for (int r = base; r < base + 8; ++r) {
        float acc = c0 * rsum[r];
        a2s[r] = acc;
        float zarg = acc * Wz + c0 * Uz;
        float wt   = acc * Wh;
        if (zarg <= -200.f) { h2s[r] = c0; }                   // z==0 exactly
        else if (zarg >= 200.f && fabsf(wt) - fabsf(c0 * Uh) >= 30.f) {
          h2s[r] = copysignf(1.f, wt);                         // z==1, tanh saturated
        } else {
          atomicOr(&rbits[r >> 5], 1u << (r & 31)); atomicAdd(&s_nresc, 1);
        }
      }
    } else {
      for (int r = base; r < base + 8; ++r) atomicOr(&rbits[r >> 5], 1u << (r & 31));
      if (tid == 0) atomicAdd(&s_nresc, N_NODES);
    }
  }
  __syncthreads();
  if (s_nresc > 0) {   // cooperative exact rescue (never fires when certs hold)
    for (int w = 0; w < 256; ++w) {
      unsigned int bits = rbits[w];
      while (bits) {
        int b = __ffs(bits) - 1; bits &= bits - 1;
        int i = w * 32 + b;
        float acc = block_dot_8192(adj + (size_t)i * N_NODES, (const float4*)h1,
                                   wred, tid, wave, lane);
        if (tid == 0) { a2s[i] = acc; h2s[i] = gru_update(acc, h1[i], Wz, Uz, Wr, Ur, Wh, Uh); }
      }
    }
  }
  __syncthreads();

  // ================= phase B: GGNN step 3 =================
  if (tid == 0) { s_same = 1; s_eqc = 1; s_nresc = 0; }
  if (tid < 256) rbits[tid] = 0u;
  __syncthreads();
  const float c1 = h2s[0];
  {
    const float4* hc4 = (const float4*)h2s;
    const float4* hp4 = (const float4*)h1;
    int same = 1, eqc = 1;
    for (int i = tid; i < N_NODES / 4; i += 1024) {
      float4 x = hc4[i], y = hp4[i];
      same &= (x.x == y.x) & (x.y == y.y) & (x.z == y.z) & (x.w == y.w);
      eqc  &= (x.x == c1) & (x.y == c1) & (x.z == c1) & (x.w == c1);
    }
    if (!same) atomicAnd(&s_same, 0);
    if (!eqc)  atomicAnd(&s_eqc, 0);
  }
  __syncthreads();
  {
    const int fsame = s_same, feqc = s_eqc;
    if (fsame) {
      for (int r = base; r < base + 8; ++r) {
        float acc = a2s[r];
        keyz[r] = __float_as_uint(gru_update(acc, h2s[r], Wz, Uz, Wr, Ur, Wh, Uh));
      }
    } else if (feqc) {
      for (int r = base; r < base + 8; ++r) {
        float acc = c1 * rsum[r];
        float zarg = acc * Wz + c1 * Uz;
        float wt   = acc * Wh;
        if (zarg <= -200.f) { keyz[r] = __float_as_uint(c1); }
        else if (zarg >= 200.f && fabsf(wt) - fabsf(c1 * Uh) >= 30.f) {
          keyz[r] = __float_as_uint(copysignf(1.f, wt));
        } else {
          atomicOr(&rbits[r >> 5], 1u << (r & 31)); atomicAdd(&s_nresc, 1);
        }
      }
    } else {
      for (int r = base; r < base + 8; ++r) atomicOr(&rbits[r >> 5], 1u << (r & 31));
      if (tid == 0) atomicAdd(&s_nresc, N_NODES);
    }
  }
  __syncthreads();
  if (s_nresc > 0) {
    for (int w = 0; w < 256; ++w) {
      unsigned int bits = rbits[w];
      while (bits) {
        int b = __ffs(bits) - 1; bits &= bits - 1;
        int i = w * 32 + b;
        float acc = block_dot_8192(adj + (size_t)i * N_NODES, (const float4*)h2s,
                                   wred, tid, wave, lane);
        if (tid == 0)
          keyz[i] = __float_as_uint(gru_update(acc, h2s[i], Wz, Uz, Wr, Ur, Wh, Uh));
      }
    }
  }
  __syncthreads();

  // ================= phase C: exact stable top-KEEP select =================
  for (int i = tid; i < N_NODES; i += 1024) {
    unsigned int u = keyz[i];
    keyz[i] = (u & 0x80000000u) ? ~u : (u | 0x80000000u);   // monotone f32->u32
  }
  if (tid == 0) { sh_prefix = 0u; sh_r = KEEP; }
  __syncthreads();

  for (int pass = 0; pass < 4; ++pass) {
    const int shift = 24 - pass * 8;
    if (tid < 256) hist[tid] = 0u;
    __syncthreads();
    const unsigned int pref = sh_prefix;
    const unsigned int r    = sh_r;
    #pragma unroll
    for (int i = 0; i < 8; ++i) {
      unsigned int k = keyz[base + i];
      bool match = (pass == 0) || ((k >> (shift + 8)) == pref);
      unsigned int d = match ? ((k >> shift) & 255u) : 256u;
      unsigned long long m = ~0ull;
      #pragma unroll
      for (int b = 0; b < 9; ++b) {
        unsigned long long bal = __ballot((d >> b) & 1u);
        m &= ((d >> b) & 1u) ? bal : ~bal;
      }
      int leader = __ffsll((unsigned long long)m) - 1;
      if (lane == leader && d < 256u)
        atomicAdd(&hist[d], (unsigned int)__popcll(m));
    }
    __syncthreads();
    if (wave == 0) {
      unsigned int t0 = hist[lane * 4], t1 = hist[lane * 4 + 1];
      unsigned int t2 = hist[lane * 4 + 2], t3 = hist[lane * 4 + 3];
      unsigned int tot = t0 + t1 + t2 + t3;
      unsigned int sc = tot;
      #pragma unroll
      for (int off = 1; off < 64; off <<= 1) {
        unsigned int o = __shfl_up(sc, off);
        if (lane >= off) sc += o;
      }
      unsigned int e = sc - tot;
      unsigned int p0 = e + t0, p1 = p0 + t1, p2 = p1 + t2, p3 = p2 + t3;
      if (r > e  && r <= p0) { sh_b = lane * 4;     sh_newr = r - e;  }
      if (r > p0 && r <= p1) { sh_b = lane * 4 + 1; sh_newr = r - p0; }
      if (r > p1 && r <= p2) { sh_b = lane * 4 + 2; sh_newr = r - p1; }
      if (r > p2 && r <= p3) { sh_b = lane * 4 + 3; sh_newr = r - p2; }
    }
    __syncthreads();
    if (tid == 0) { sh_prefix = (pref << 8) | sh_b; sh_r = sh_newr; }
    __syncthreads();
  }
  const unsigned int Kk = sh_prefix;
  const unsigned int tk = sh_r;

  unsigned int eqc = 0;
  #pragma unroll
  for (int i = 0; i < 8; ++i) eqc += (keyz[base + i] == Kk) ? 1u : 0u;
  const unsigned int eqbase = block_excl_scan_1024(eqc, wsum, wave, lane, tid);

  unsigned int runeq = eqbase, kc = 0;
  #pragma unroll
  for (int i = 0; i < 8; ++i) {
    unsigned int k = keyz[base + i];
    bool kp;
    if (k == Kk) { kp = (runeq < tk); ++runeq; } else kp = (k < Kk);
    kc += kp ? 1u : 0u;
  }
  unsigned int pos = block_excl_scan_1024(kc, wsum, wave, lane, tid);

  runeq = eqbase;
  #pragma unroll
  for (int i = 0; i < 8; ++i) {
    unsigned int k = keyz[base + i];
    bool kp;
    if (k == Kk) { kp = (runeq < tk); ++runeq; } else kp = (k < Kk);
    mask_out[base + i] = kp ? 1.0f : 0.0f;
    if (kp) keep_idx[pos++] = base + i;
  }
}

// ---------------- gather kept rows (float4: rows are 75 aligned float4) ----------------
__global__ __launch_bounds__(256) void gather_kernel(
    const float* __restrict__ He, const int* __restrict__ keep_idx,
    float* __restrict__ out) {
  int t = blockIdx.x * 256 + threadIdx.x;
  if (t >= KEEP * (HIDDEN / 4)) return;
  int p = t / (HIDDEN / 4);
  int c = t - p * (HIDDEN / 4);
  const float4* src = (const float4*)(He + (size_t)keep_idx[p] * HIDDEN);
  ((float4*)out)[t] = src[c];
}

extern "C" void kernel_launch(void* const* d_in, const int* in_sizes, int n_in,
                              void* d_out, int out_size, void* d_ws, size_t ws_size,
                              hipStream_t stream) {
  const float* He  = (const float*)d_in[0];
  const float* Hc  = (const float*)d_in[1];
  const float* adj = (const float*)d_in[2];
  const float* W1  = (const float*)d_in[3];
  const float* Wz  = (const float*)d_in[4];
  const float* Uz  = (const float*)d_in[5];
  const float* Wr  = (const float*)d_in[6];
  const float* Ur  = (const float*)d_in[7];
  const float* Wh  = (const float*)d_in[8];
  const float* Uh  = (const float*)d_in[9];
  float* out = (float*)d_out;

  float* ws   = (float*)d_ws;
  float* h0   = ws;                        // [8192]
  float* h1   = ws + 1 * N_NODES;
  float* a1   = ws + 2 * N_NODES;
  float* rsum = ws + 3 * N_NODES;
  int* keep_idx = (int*)(ws + 4 * N_NODES);

  float* mask_out = out + (size_t)KEEP * HIDDEN;

  score_prep_kernel  <<<N_NODES / 32, 512, 0, stream>>>(He, Hc, W1, h0);
  ggnn_step1         <<<N_NODES / 4, 256, 0, stream>>>(adj, h0, h1, a1, rsum,
                                                       Wz, Uz, Wr, Ur, Wh, Uh);
  fused_refine_select<<<1, 1024, 0, stream>>>(h0, h1, a1, rsum, adj, mask_out, keep_idx,
                                              Wz, Uz, Wr, Ur, Wh, Uh);
  gather_kernel      <<<(KEEP * (HIDDEN / 4) + 255) / 256, 256, 0, stream>>>(He, keep_idx, out);
}

// Round 7
// 126.599 us; speedup vs baseline: 1.8019x; 1.0086x over previous
//
#include <hip/hip_runtime.h>
#include <math.h>

#define N_NODES 8192
#define N_CLAIM 128
#define HIDDEN  300
#define KEEP    5735   // N - int(0.3*N) = 8192 - 2457
#define KC      50
#define SHCP    132    // padded LDS stride for transposed Hc chunk

// ---------------- score (+prep folded): 4 nodes/wave, k-paired float2 LDS ----------------
// score = 0.5*(He@W1) + 0.5*(-log( softmax(He@Hc^T) @ rowsum(Hc) + 1e-10 ))
__global__ __launch_bounds__(512) void score_prep_kernel(
    const float* __restrict__ He, const float* __restrict__ Hc,
    const float* __restrict__ W1, float* __restrict__ score_out) {
  __shared__ float she[32][HIDDEN];    // 38.4 KB
  __shared__ float shc[KC][SHCP];      // 26.4 KB (padded stride breaks bank conflicts)
  const int tid  = threadIdx.x;
  const int wave = tid >> 6, lane = tid & 63;
  const int nb   = blockIdx.x * 32;

  {  // stage 32 contiguous He rows (float4)
    const float4* src4 = (const float4*)(He + (size_t)nb * HIDDEN);
    float4* dst4 = (float4*)&she[0][0];
    for (int i = tid; i < 32 * HIDDEN / 4; i += 512) dst4[i] = src4[i];
  }

  float a[4][2] = {{0.f,0.f},{0.f,0.f},{0.f,0.f},{0.f,0.f}};
  float sA = 0.f, sB = 0.f;            // per-lane claim sums (scl for claims 2l,2l+1)
  for (int k0 = 0; k0 < HIDDEN; k0 += KC) {
    __syncthreads();
    // stage Hc chunk transposed: shc[k][j] = Hc[j][k0+k]
    for (int idx = tid; idx < N_CLAIM * (KC / 2); idx += 512) {
      int j  = idx / (KC / 2);
      int kk = idx - j * (KC / 2);
      float2 v = *(const float2*)(Hc + j * HIDDEN + k0 + 2 * kk);
      shc[2 * kk][j]     = v.x;
      shc[2 * kk + 1][j] = v.y;
    }
    __syncthreads();
    #pragma unroll 5
    for (int k = 0; k < KC; k += 2) {
      float2 ca = ((const float2*)&shc[k][0])[lane];       // claims 2l,2l+1 @ k
      float2 cb = ((const float2*)&shc[k + 1][0])[lane];   // claims 2l,2l+1 @ k+1
      sA += ca.x + cb.x;
      sB += ca.y + cb.y;
      #pragma unroll
      for (int n = 0; n < 4; ++n) {
        float2 h2v = ((const float2*)&she[wave * 4 + n][0])[(k0 + k) >> 1];  // broadcast
        a[n][0] = fmaf(h2v.x, ca.x, fmaf(h2v.y, cb.x, a[n][0]));
        a[n][1] = fmaf(h2v.x, ca.y, fmaf(h2v.y, cb.y, a[n][1]));
      }
    }
  }

  float res[4];
  #pragma unroll
  for (int n = 0; n < 4; ++n) {
    float m = fmaxf(a[n][0], a[n][1]);
    #pragma unroll
    for (int s = 32; s; s >>= 1) m = fmaxf(m, __shfl_xor(m, s));
    float e0 = expf(a[n][0] - m), e1 = expf(a[n][1] - m);
    float den = e0 + e1, num = e0 * sA + e1 * sB;
    #pragma unroll
    for (int s = 32; s; s >>= 1) { den += __shfl_xor(den, s); num += __shfl_xor(num, s); }
    float s1 = 0.f;
    for (int k = lane; k < HIDDEN; k += 64) s1 = fmaf(she[wave * 4 + n][k], W1[k], s1);
    #pragma unroll
    for (int s = 32; s; s >>= 1) s1 += __shfl_xor(s1, s);
    res[n] = 0.5f * s1 + 0.5f * (-logf(num / den + 1e-10f));
  }
  if (lane == 0) {
    int n0 = nb + wave * 4;
    #pragma unroll
    for (int n = 0; n < 4; ++n) score_out[n0 + n] = res[n];
  }
}

// ---------------- GRU epilogue ----------------
__device__ inline float gru_update(float acc, float hi,
                                   float Wz, float Uz, float Wr, float Ur,
                                   float Wh, float Uh) {
  float z  = 1.f / (1.f + expf(-(acc * Wz + hi * Uz)));
  float r  = 1.f / (1.f + expf(-(acc * Wr + hi * Ur)));
  float ht = tanhf(acc * Wh + (r * hi) * Uh);
  return (1.f - z) * hi + z * ht;
}

// ---------------- GGNN step 1: wide-front cooperative matvec + rowsum ----------------
// 1024 threads, 16 consecutive rows per block. h slice lives in registers (2 float4/thread).
// Per row: contiguous 32 KB front (2 float4/thread), next row prefetched before the reduce.
__global__ __launch_bounds__(1024, 8) void ggnn_step1(
    const float* __restrict__ adj, const float* __restrict__ h_in,
    float* __restrict__ h_out, float* __restrict__ a_out,
    float* __restrict__ rowsum_out,
    const float* __restrict__ pWz, const float* __restrict__ pUz,
    const float* __restrict__ pWr, const float* __restrict__ pUr,
    const float* __restrict__ pWh, const float* __restrict__ pUh) {
  __shared__ float s_wa[16], s_wq[16];   // per-wave partials (one row at a time)
  __shared__ float s_a[16], s_rs[16];    // per-row results
  const int tid  = threadIdx.x;
  const int wave = tid >> 6, lane = tid & 63;
  const int rbase = blockIdx.x * 16;

  const float4* __restrict__ h4 = (const float4*)h_in;
  const float4 hA = h4[tid];            // columns 4t .. 4t+3
  const float4 hB = h4[tid + 1024];     // columns 4096+4t ..

  const float4* __restrict__ arow = (const float4*)(adj + (size_t)rbase * N_NODES);
  float4 aA = arow[tid];
  float4 aB = arow[tid + 1024];

  #pragma unroll 1
  for (int r = 0; r < 16; ++r) {
    float4 nA = aA, nB = aB;
    if (r < 15) {                        // prefetch next row before reducing this one
      const float4* nrow = arow + (size_t)(r + 1) * (N_NODES / 4);
      nA = nrow[tid];
      nB = nrow[tid + 1024];
    }
    float p = aA.x * hA.x;
    p = fmaf(aA.y, hA.y, p); p = fmaf(aA.z, hA.z, p); p = fmaf(aA.w, hA.w, p);
    p = fmaf(aB.x, hB.x, p); p = fmaf(aB.y, hB.y, p);
    p = fmaf(aB.z, hB.z, p); p = fmaf(aB.w, hB.w, p);
    float q = (aA.x + aA.y) + (aA.z + aA.w) + (aB.x + aB.y) + (aB.z + aB.w);
    #pragma unroll
    for (int s = 32; s; s >>= 1) { p += __shfl_xor(p, s); q += __shfl_xor(q, s); }
    if (lane == 0) { s_wa[wave] = p; s_wq[wave] = q; }
    __syncthreads();
    if (wave == 0) {
      float pa = (lane < 16) ? s_wa[lane] : 0.f;
      float qa = (lane < 16) ? s_wq[lane] : 0.f;
      #pragma unroll
      for (int s = 8; s; s >>= 1) { pa += __shfl_xor(pa, s); qa += __shfl_xor(qa, s); }
      if (lane == 0) { s_a[r] = pa; s_rs[r] = qa; }
    }
    __syncthreads();                     // protects s_wa/s_wq reuse next row
    aA = nA; aB = nB;
  }

  if (wave == 0 && lane < 16) {
    const int row = rbase + lane;
    const float acc = s_a[lane], rs = s_rs[lane];
    a_out[row] = acc;
    rowsum_out[row] = rs;
    h_out[row] = gru_update(acc, h_in[row],
                            pWz[0], pUz[0], pWr[0], pUr[0], pWh[0], pUh[0]);
  }
}

// ---------------- fused: steps 2+3 (certified fast paths) + exact stable select ----------------
__device__ inline unsigned int block_excl_scan_1024(unsigned int v, unsigned int* wsum,
                                                    int wave, int lane, int tid) {
  unsigned int sc = v;
  #pragma unroll
  for (int off = 1; off < 64; off <<= 1) {
    unsigned int o = __shfl_up(sc, off);
    if (lane >= off) sc += o;
  }
  __syncthreads();
  if (lane == 63) wsum[wave] = sc;
  __syncthreads();
  if (tid == 0) {
    unsigned int run = 0;
    for (int w = 0; w < 16; ++w) { unsigned int t = wsum[w]; wsum[w] = run; run += t; }
  }
  __syncthreads();
  return wsum[wave] + sc - v;
}

// cooperative full-row dot (rescue path; exact fp32, never fires for certified data)
__device__ inline float block_dot_8192(const float* __restrict__ adjrow,
                                       const float4* __restrict__ h4,
                                       float* wred, int tid, int wave, int lane) {
  const float4* a4 = (const float4*)adjrow;
  float acc = 0.f;
  #pragma unroll
  for (int it = 0; it < 2; ++it) {
    int idx = tid + it * 1024;               // 2048 float4 per row
    float4 a = a4[idx]; float4 h = h4[idx];
    acc = fmaf(a.x, h.x, fmaf(a.y, h.y, fmaf(a.z, h.z, fmaf(a.w, h.w, acc))));
  }
  #pragma unroll
  for (int s = 32; s; s >>= 1) acc += __shfl_xor(acc, s);
  if (lane == 0) wred[wave] = acc;
  __syncthreads();
  if (tid == 0) { float t = 0.f; for (int w = 0; w < 16; ++w) t += wred[w]; wred[0] = t; }
  __syncthreads();
  float r = wred[0];
  __syncthreads();
  return r;
}

__global__ __launch_bounds__(1024) void fused_refine_select(
    const float* __restrict__ h0, const float* __restrict__ h1,
    const float* __restrict__ a1, const float* __restrict__ rsum,
    const float* __restrict__ adj,
    float* __restrict__ mask_out, int* __restrict__ keep_idx,
    const float* __restrict__ pWz, const float* __restrict__ pUz,
    const float* __restrict__ pWr, const float* __restrict__ pUr,
    const float* __restrict__ pWh, const float* __restrict__ pUh) {
  __shared__ float h2s[N_NODES];           // 32 KB
  __shared__ float a2s[N_NODES];           // 32 KB
  __shared__ unsigned int keyz[N_NODES];   // 32 KB
  __shared__ unsigned int hist[256];
  __shared__ unsigned int rbits[256];
  __shared__ unsigned int wsum[16];
  __shared__ float wred[16];
  __shared__ int s_same, s_eqc, s_nresc;
  __shared__ unsigned int sh_b, sh_newr, sh_prefix, sh_r;

  const int tid = threadIdx.x;
  const int wave = tid >> 6, lane = tid & 63;
  const int base = tid * 8;
  const float Wz = pWz[0], Uz = pUz[0], Wr = pWr[0], Ur = pUr[0];
  const float Wh = pWh[0], Uh = pUh[0];

  // ================= phase A: GGNN step 2 =================
  if (tid == 0) { s_same = 1; s_eqc = 1; s_nresc = 0; }
  if (tid < 256) rbits[tid] = 0u;
  __syncthreads();
  const float c0 = h1[0];
  {
    const float4* hc4 = (const float4*)h1;
    const float4* hp4 = (const float4*)h0;
    int same = 1, eqc = 1;
    for (int i = tid; i < N_NODES / 4; i += 1024) {
      float4 x = hc4[i], y = hp4[i];
      same &= (x.x == y.x) & (x.y == y.y) & (x.z == y.z) & (x.w == y.w);
      eqc  &= (x.x == c0) & (x.y == c0) & (x.z == c0) & (x.w == c0);
    }
    if (!same) atomicAnd(&s_same, 0);
    if (!eqc)  atomicAnd(&s_eqc, 0);
  }
  __syncthreads();
  {
    const int fsame = s_same, feqc = s_eqc;
    if (fsame) {
      for (int r = base; r < base + 8; ++r) {
        float acc = a1[r];                   // adj@h1 == adj@h0 bitwise
        a2s[r] = acc;
        h2s[r] = gru_update(acc, h1[r], Wz, Uz, Wr, Ur, Wh, Uh);
      }
    } else if (feqc) {
      for (int r = base; r < base + 8; ++r) {
        float acc = c0 * rsum[r];
        a2s[r] = acc;
        float zarg = acc * Wz + c0 * Uz;
        float wt   = acc * Wh;
        if (zarg <= -200.f) { h2s[r] = c0; }                   // z==0 exactly
        else if (zarg >= 200.f && fabsf(wt) - fabsf(c0 * Uh) >= 30.f) {
          h2s[r] = copysignf(1.f, wt);                         // z==1, tanh saturated
        } else {
          atomicOr(&rbits[r >> 5], 1u << (r & 31)); atomicAdd(&s_nresc, 1);
        }
      }
    } else {
      for (int r = base; r < base + 8; ++r) atomicOr(&rbits[r >> 5], 1u << (r & 31));
      if (tid == 0) atomicAdd(&s_nresc, N_NODES);
    }
  }
  __syncthreads();
  if (s_nresc > 0) {   // cooperative exact rescue (never fires when certs hold)
    for (int w = 0; w < 256; ++w) {
      unsigned int bits = rbits[w];
      while (bits) {
        int b = __ffs(bits) - 1; bits &= bits - 1;
        int i = w * 32 + b;
        float acc = block_dot_8192(adj + (size_t)i * N_NODES, (const float4*)h1,
                                   wred, tid, wave, lane);
        if (tid == 0) { a2s[i] = acc; h2s[i] = gru_update(acc, h1[i], Wz, Uz, Wr, Ur, Wh, Uh); }
      }
    }
  }
  __syncthreads();

  // ================= phase B: GGNN step 3 =================
  if (tid == 0) { s_same = 1; s_eqc = 1; s_nresc = 0; }
  if (tid < 256) rbits[tid] = 0u;
  __syncthreads();
  const float c1 = h2s[0];
  {
    const float4* hc4 = (const float4*)h2s;
    const float4* hp4 = (const float4*)h1;
    int same = 1, eqc = 1;
    for (int i = tid; i < N_NODES / 4; i += 1024) {
      float4 x = hc4[i], y = hp4[i];
      same &= (x.x == y.x) & (x.y == y.y) & (x.z == y.z) & (x.w == y.w);
      eqc  &= (x.x == c1) & (x.y == c1) & (x.z == c1) & (x.w == c1);
    }
    if (!same) atomicAnd(&s_same, 0);
    if (!eqc)  atomicAnd(&s_eqc, 0);
  }
  __syncthreads();
  {
    const int fsame = s_same, feqc = s_eqc;
    if (fsame) {
      for (int r = base; r < base + 8; ++r) {
        float acc = a2s[r];
        keyz[r] = __float_as_uint(gru_update(acc, h2s[r], Wz, Uz, Wr, Ur, Wh, Uh));
      }
    } else if (feqc) {
      for (int r = base; r < base + 8; ++r) {
        float acc = c1 * rsum[r];
        float zarg = acc * Wz + c1 * Uz;
        float wt   = acc * Wh;
        if (zarg <= -200.f) { keyz[r] = __float_as_uint(c1); }
        else if (zarg >= 200.f && fabsf(wt) - fabsf(c1 * Uh) >= 30.f) {
          keyz[r] = __float_as_uint(copysignf(1.f, wt));
        } else {
          atomicOr(&rbits[r >> 5], 1u << (r & 31)); atomicAdd(&s_nresc, 1);
        }
      }
    } else {
      for (int r = base; r < base + 8; ++r) atomicOr(&rbits[r >> 5], 1u << (r & 31));
      if (tid == 0) atomicAdd(&s_nresc, N_NODES);
    }
  }
  __syncthreads();
  if (s_nresc > 0) {
    for (int w = 0; w < 256; ++w) {
      unsigned int bits = rbits[w];
      while (bits) {
        int b = __ffs(bits) - 1; bits &= bits - 1;
        int i = w * 32 + b;
        float acc = block_dot_8192(adj + (size_t)i * N_NODES, (const float4*)h2s,
                                   wred, tid, wave, lane);
        if (tid == 0)
          keyz[i] = __float_as_uint(gru_update(acc, h2s[i], Wz, Uz, Wr, Ur, Wh, Uh));
      }
    }
  }
  __syncthreads();

  // ================= phase C: exact stable top-KEEP select =================
  for (int i = tid; i < N_NODES; i += 1024) {
    unsigned int u = keyz[i];
    keyz[i] = (u & 0x80000000u) ? ~u : (u | 0x80000000u);   // monotone f32->u32
  }
  if (tid == 0) { sh_prefix = 0u; sh_r = KEEP; }
  __syncthreads();

  for (int pass = 0; pass < 4; ++pass) {
    const int shift = 24 - pass * 8;
    if (tid < 256) hist[tid] = 0u;
    __syncthreads();
    const unsigned int pref = sh_prefix;
    const unsigned int r    = sh_r;
    #pragma unroll
    for (int i = 0; i < 8; ++i) {
      unsigned int k = keyz[base + i];
      bool match = (pass == 0) || ((k >> (shift + 8)) == pref);
      unsigned int d = match ? ((k >> shift) & 255u) : 256u;
      unsigned long long m = ~0ull;
      #pragma unroll
      for (int b = 0; b < 9; ++b) {
        unsigned long long bal = __ballot((d >> b) & 1u);
        m &= ((d >> b) & 1u) ? bal : ~bal;
      }
      int leader = __ffsll((unsigned long long)m) - 1;
      if (lane == leader && d < 256u)
        atomicAdd(&hist[d], (unsigned int)__popcll(m));
    }
    __syncthreads();
    if (wave == 0) {
      unsigned int t0 = hist[lane * 4], t1 = hist[lane * 4 + 1];
      unsigned int t2 = hist[lane * 4 + 2], t3 = hist[lane * 4 + 3];
      unsigned int tot = t0 + t1 + t2 + t3;
      unsigned int sc = tot;
      #pragma unroll
      for (int off = 1; off < 64; off <<= 1) {
        unsigned int o = __shfl_up(sc, off);
        if (lane >= off) sc += o;
      }
      unsigned int e = sc - tot;
      unsigned int p0 = e + t0, p1 = p0 + t1, p2 = p1 + t2, p3 = p2 + t3;
      if (r > e  && r <= p0) { sh_b = lane * 4;     sh_newr = r - e;  }
      if (r > p0 && r <= p1) { sh_b = lane * 4 + 1; sh_newr = r - p0; }
      if (r > p1 && r <= p2) { sh_b = lane * 4 + 2; sh_newr = r - p1; }
      if (r > p2 && r <= p3) { sh_b = lane * 4 + 3; sh_newr = r - p2; }
    }
    __syncthreads();
    if (tid == 0) { sh_prefix = (pref << 8) | sh_b; sh_r = sh_newr; }
    __syncthreads();
  }
  const unsigned int Kk = sh_prefix;
  const unsigned int tk = sh_r;

  unsigned int eqc = 0;
  #pragma unroll
  for (int i = 0; i < 8; ++i) eqc += (keyz[base + i] == Kk) ? 1u : 0u;
  const unsigned int eqbase = block_excl_scan_1024(eqc, wsum, wave, lane, tid);

  unsigned int runeq = eqbase, kc = 0;
  #pragma unroll
  for (int i = 0; i < 8; ++i) {
    unsigned int k = keyz[base + i];
    bool kp;
    if (k == Kk) { kp = (runeq < tk); ++runeq; } else kp = (k < Kk);
    kc += kp ? 1u : 0u;
  }
  unsigned int pos = block_excl_scan_1024(kc, wsum, wave, lane, tid);

  runeq = eqbase;
  #pragma unroll
  for (int i = 0; i < 8; ++i) {
    unsigned int k = keyz[base + i];
    bool kp;
    if (k == Kk) { kp = (runeq < tk); ++runeq; } else kp = (k < Kk);
    mask_out[base + i] = kp ? 1.0f : 0.0f;
    if (kp) keep_idx[pos++] = base + i;
  }
}

// ---------------- gather kept rows (float4: rows are 75 aligned float4) ----------------
__global__ __launch_bounds__(256) void gather_kernel(
    const float* __restrict__ He, const int* __restrict__ keep_idx,
    float* __restrict__ out) {
  int t = blockIdx.x * 256 + threadIdx.x;
  if (t >= KEEP * (HIDDEN / 4)) return;
  int p = t / (HIDDEN / 4);
  int c = t - p * (HIDDEN / 4);
  const float4* src = (const float4*)(He + (size_t)keep_idx[p] * HIDDEN);
  ((float4*)out)[t] = src[c];
}

extern "C" void kernel_launch(void* const* d_in, const int* in_sizes, int n_in,
                              void* d_out, int out_size, void* d_ws, size_t ws_size,
                              hipStream_t stream) {
  const float* He  = (const float*)d_in[0];
  const float* Hc  = (const float*)d_in[1];
  const float* adj = (const float*)d_in[2];
  const float* W1  = (const float*)d_in[3];
  const float* Wz  = (const float*)d_in[4];
  const float* Uz  = (const float*)d_in[5];
  const float* Wr  = (const float*)d_in[6];
  const float* Ur  = (const float*)d_in[7];
  const float* Wh  = (const float*)d_in[8];
  const float* Uh  = (const float*)d_in[9];
  float* out = (float*)d_out;

  float* ws   = (float*)d_ws;
  float* h0   = ws;                        // [8192]
  float* h1   = ws + 1 * N_NODES;
  float* a1   = ws + 2 * N_NODES;
  float* rsum = ws + 3 * N_NODES;
  int* keep_idx = (int*)(ws + 4 * N_NODES);

  float* mask_out = out + (size_t)KEEP * HIDDEN;

  score_prep_kernel  <<<N_NODES / 32, 512, 0, stream>>>(He, Hc, W1, h0);
  ggnn_step1         <<<N_NODES / 16, 1024, 0, stream>>>(adj, h0, h1, a1, rsum,
                                                         Wz, Uz, Wr, Ur, Wh, Uh);
  fused_refine_select<<<1, 1024, 0, stream>>>(h0, h1, a1, rsum, adj, mask_out, keep_idx,
                                              Wz, Uz, Wr, Ur, Wh, Uh);
  gather_kernel      <<<(KEEP * (HIDDEN / 4) + 255) / 256, 256, 0, stream>>>(He, keep_idx, out);
}

// Round 8
// 125.969 us; speedup vs baseline: 1.8109x; 1.0050x over previous
//
#include <hip/hip_runtime.h>
#include <math.h>

#define N_NODES 8192
#define N_CLAIM 128
#define HIDDEN  300
#define KEEP    5735   // N - int(0.3*N) = 8192 - 2457
#define KC      50
#define SHCP    132    // padded LDS stride for transposed Hc chunk
#define KP(x)   ((x) + ((x) >> 5))   // bank-deconflict skew for per-thread-contiguous LDS
#define NPAD    (N_NODES + (N_NODES >> 5))   // 8448 words

// ---------------- score (+prep folded): 4 nodes/wave, k-paired float2 LDS ----------------
// score = 0.5*(He@W1) + 0.5*(-log( softmax(He@Hc^T) @ rowsum(Hc) + 1e-10 ))
__global__ __launch_bounds__(512) void score_prep_kernel(
    const float* __restrict__ He, const float* __restrict__ Hc,
    const float* __restrict__ W1, float* __restrict__ score_out) {
  __shared__ float she[32][HIDDEN];    // 38.4 KB
  __shared__ float shc[KC][SHCP];      // 26.4 KB (padded stride breaks bank conflicts)
  const int tid  = threadIdx.x;
  const int wave = tid >> 6, lane = tid & 63;
  const int nb   = blockIdx.x * 32;

  {  // stage 32 contiguous He rows (float4)
    const float4* src4 = (const float4*)(He + (size_t)nb * HIDDEN);
    float4* dst4 = (float4*)&she[0][0];
    for (int i = tid; i < 32 * HIDDEN / 4; i += 512) dst4[i] = src4[i];
  }

  float a[4][2] = {{0.f,0.f},{0.f,0.f},{0.f,0.f},{0.f,0.f}};
  float sA = 0.f, sB = 0.f;            // per-lane claim sums (scl for claims 2l,2l+1)
  for (int k0 = 0; k0 < HIDDEN; k0 += KC) {
    __syncthreads();
    // stage Hc chunk transposed: shc[k][j] = Hc[j][k0+k]
    for (int idx = tid; idx < N_CLAIM * (KC / 2); idx += 512) {
      int j  = idx / (KC / 2);
      int kk = idx - j * (KC / 2);
      float2 v = *(const float2*)(Hc + j * HIDDEN + k0 + 2 * kk);
      shc[2 * kk][j]     = v.x;
      shc[2 * kk + 1][j] = v.y;
    }
    __syncthreads();
    #pragma unroll 5
    for (int k = 0; k < KC; k += 2) {
      float2 ca = ((const float2*)&shc[k][0])[lane];       // claims 2l,2l+1 @ k
      float2 cb = ((const float2*)&shc[k + 1][0])[lane];   // claims 2l,2l+1 @ k+1
      sA += ca.x + cb.x;
      sB += ca.y + cb.y;
      #pragma unroll
      for (int n = 0; n < 4; ++n) {
        float2 h2v = ((const float2*)&she[wave * 4 + n][0])[(k0 + k) >> 1];  // broadcast
        a[n][0] = fmaf(h2v.x, ca.x, fmaf(h2v.y, cb.x, a[n][0]));
        a[n][1] = fmaf(h2v.x, ca.y, fmaf(h2v.y, cb.y, a[n][1]));
      }
    }
  }

  float res[4];
  #pragma unroll
  for (int n = 0; n < 4; ++n) {
    float m = fmaxf(a[n][0], a[n][1]);
    #pragma unroll
    for (int s = 32; s; s >>= 1) m = fmaxf(m, __shfl_xor(m, s));
    float e0 = expf(a[n][0] - m), e1 = expf(a[n][1] - m);
    float den = e0 + e1, num = e0 * sA + e1 * sB;
    #pragma unroll
    for (int s = 32; s; s >>= 1) { den += __shfl_xor(den, s); num += __shfl_xor(num, s); }
    float s1 = 0.f;
    for (int k = lane; k < HIDDEN; k += 64) s1 = fmaf(she[wave * 4 + n][k], W1[k], s1);
    #pragma unroll
    for (int s = 32; s; s >>= 1) s1 += __shfl_xor(s1, s);
    res[n] = 0.5f * s1 + 0.5f * (-logf(num / den + 1e-10f));
  }
  if (lane == 0) {
    int n0 = nb + wave * 4;
    #pragma unroll
    for (int n = 0; n < 4; ++n) score_out[n0 + n] = res[n];
  }
}

// ---------------- GRU epilogue ----------------
__device__ inline float gru_update(float acc, float hi,
                                   float Wz, float Uz, float Wr, float Ur,
                                   float Wh, float Uh) {
  float z  = 1.f / (1.f + expf(-(acc * Wz + hi * Uz)));
  float r  = 1.f / (1.f + expf(-(acc * Wr + hi * Ur)));
  float ht = tanhf(acc * Wh + (r * hi) * Uh);
  return (1.f - z) * hi + z * ht;
}

// ---------------- GGNN step 1: wide-front cooperative matvec + rowsum ----------------
__global__ __launch_bounds__(1024, 8) void ggnn_step1(
    const float* __restrict__ adj, const float* __restrict__ h_in,
    float* __restrict__ h_out, float* __restrict__ a_out,
    float* __restrict__ rowsum_out,
    const float* __restrict__ pWz, const float* __restrict__ pUz,
    const float* __restrict__ pWr, const float* __restrict__ pUr,
    const float* __restrict__ pWh, const float* __restrict__ pUh) {
  __shared__ float s_wa[16], s_wq[16];   // per-wave partials (one row at a time)
  __shared__ float s_a[16], s_rs[16];    // per-row results
  const int tid  = threadIdx.x;
  const int wave = tid >> 6, lane = tid & 63;
  const int rbase = blockIdx.x * 16;

  const float4* __restrict__ h4 = (const float4*)h_in;
  const float4 hA = h4[tid];            // columns 4t .. 4t+3
  const float4 hB = h4[tid + 1024];     // columns 4096+4t ..

  const float4* __restrict__ arow = (const float4*)(adj + (size_t)rbase * N_NODES);
  float4 aA = arow[tid];
  float4 aB = arow[tid + 1024];

  #pragma unroll 1
  for (int r = 0; r < 16; ++r) {
    float4 nA = aA, nB = aB;
    if (r < 15) {                        // prefetch next row before reducing this one
      const float4* nrow = arow + (size_t)(r + 1) * (N_NODES / 4);
      nA = nrow[tid];
      nB = nrow[tid + 1024];
    }
    float p = aA.x * hA.x;
    p = fmaf(aA.y, hA.y, p); p = fmaf(aA.z, hA.z, p); p = fmaf(aA.w, hA.w, p);
    p = fmaf(aB.x, hB.x, p); p = fmaf(aB.y, hB.y, p);
    p = fmaf(aB.z, hB.z, p); p = fmaf(aB.w, hB.w, p);
    float q = (aA.x + aA.y) + (aA.z + aA.w) + (aB.x + aB.y) + (aB.z + aB.w);
    #pragma unroll
    for (int s = 32; s; s >>= 1) { p += __shfl_xor(p, s); q += __shfl_xor(q, s); }
    if (lane == 0) { s_wa[wave] = p; s_wq[wave] = q; }
    __syncthreads();
    if (wave == 0) {
      float pa = (lane < 16) ? s_wa[lane] : 0.f;
      float qa = (lane < 16) ? s_wq[lane] : 0.f;
      #pragma unroll
      for (int s = 8; s; s >>= 1) { pa += __shfl_xor(pa, s); qa += __shfl_xor(qa, s); }
      if (lane == 0) { s_a[r] = pa; s_rs[r] = qa; }
    }
    __syncthreads();                     // protects s_wa/s_wq reuse next row
    aA = nA; aB = nB;
  }

  if (wave == 0 && lane < 16) {
    const int row = rbase + lane;
    const float acc = s_a[lane], rs = s_rs[lane];
    a_out[row] = acc;
    rowsum_out[row] = rs;
    h_out[row] = gru_update(acc, h_in[row],
                            pWz[0], pUz[0], pWr[0], pUr[0], pWh[0], pUh[0]);
  }
}

// ---------------- fused: steps 2+3 (certified fast paths) + exact stable select ----------------
__device__ inline unsigned int block_excl_scan_1024(unsigned int v, unsigned int* wsum,
                                                    int wave, int lane, int tid) {
  unsigned int sc = v;
  #pragma unroll
  for (int off = 1; off < 64; off <<= 1) {
    unsigned int o = __shfl_up(sc, off);
    if (lane >= off) sc += o;
  }
  __syncthreads();
  if (lane == 63) wsum[wave] = sc;
  __syncthreads();
  if (tid == 0) {
    unsigned int run = 0;
    for (int w = 0; w < 16; ++w) { unsigned int t = wsum[w]; wsum[w] = run; run += t; }
  }
  __syncthreads();
  return wsum[wave] + sc - v;
}

// cooperative full-row dot (rescue path; exact fp32, never fires for certified data)
__device__ inline float block_dot_8192(const float* __restrict__ adjrow,
                                       const float4* __restrict__ h4,
                                       float* wred, int tid, int wave, int lane) {
  const float4* a4 = (const float4*)adjrow;
  float acc = 0.f;
  #pragma unroll
  for (int it = 0; it < 2; ++it) {
    int idx = tid + it * 1024;               // 2048 float4 per row
    float4 a = a4[idx]; float4 h = h4[idx];
    acc = fmaf(a.x, h.x, fmaf(a.y, h.y, fmaf(a.z, h.z, fmaf(a.w, h.w, acc))));
  }
  #pragma unroll
  for (int s = 32; s; s >>= 1) acc += __shfl_xor(acc, s);
  if (lane == 0) wred[wave] = acc;
  __syncthreads();
  if (tid == 0) { float t = 0.f; for (int w = 0; w < 16; ++w) t += wred[w]; wred[0] = t; }
  __syncthreads();
  float r = wred[0];
  __syncthreads();
  return r;
}

__global__ __launch_bounds__(1024) void fused_refine_select(
    const float* __restrict__ h0, const float* __restrict__ h1,
    const float* __restrict__ a1, const float* __restrict__ rsum,
    const float* __restrict__ adj,
    float* __restrict__ mask_out, int* __restrict__ keep_idx,
    const float* __restrict__ pWz, const float* __restrict__ pUz,
    const float* __restrict__ pWr, const float* __restrict__ pUr,
    const float* __restrict__ pWh, const float* __restrict__ pUh) {
  __shared__ float h2s[NPAD];              // 33 KB, KP-skewed
  __shared__ float a2s[NPAD];              // 33 KB, KP-skewed
  __shared__ unsigned int keyz[NPAD];      // 33 KB, KP-skewed
  __shared__ unsigned int hist[256];
  __shared__ unsigned int rbits[256];
  __shared__ unsigned int wsum[16];
  __shared__ float wred[16];
  __shared__ int s_same, s_eqc, s_nresc;
  __shared__ unsigned int sh_b, sh_newr, sh_prefix, sh_r;

  const int tid = threadIdx.x;
  const int wave = tid >> 6, lane = tid & 63;
  const int base = tid * 8;
  const float Wz = pWz[0], Uz = pUz[0], Wr = pWr[0], Ur = pUr[0];
  const float Wh = pWh[0], Uh = pUh[0];

  // ================= phase A: GGNN step 2 =================
  if (tid == 0) { s_same = 1; s_eqc = 1; s_nresc = 0; }
  if (tid < 256) rbits[tid] = 0u;
  __syncthreads();
  const float c0 = h1[0];
  {
    const float4* hc4 = (const float4*)h1;
    const float4* hp4 = (const float4*)h0;
    int same = 1, eqc = 1;
    for (int i = tid; i < N_NODES / 4; i += 1024) {
      float4 x = hc4[i], y = hp4[i];
      same &= (x.x == y.x) & (x.y == y.y) & (x.z == y.z) & (x.w == y.w);
      eqc  &= (x.x == c0) & (x.y == c0) & (x.z == c0) & (x.w == c0);
    }
    unsigned long long bs = __ballot(!same);
    unsigned long long be = __ballot(!eqc);
    if (lane == 0) {                       // <=16 LDS atomics, not 1024
      if (bs) atomicAnd(&s_same, 0);
      if (be) atomicAnd(&s_eqc, 0);
    }
  }
  __syncthreads();
  {
    const int fsame = s_same, feqc = s_eqc;
    if (fsame) {
      for (int r = base; r < base + 8; ++r) {
        float acc = a1[r];                   // adj@h1 == adj@h0 bitwise
        a2s[KP(r)] = acc;
        h2s[KP(r)] = gru_update(acc, h1[r], Wz, Uz, Wr, Ur, Wh, Uh);
      }
    } else if (feqc) {
      for (int r = base; r < base + 8; ++r) {
        float acc = c0 * rsum[r];
        a2s[KP(r)] = acc;
        float zarg = acc * Wz + c0 * Uz;
        float wt   = acc * Wh;
        if (zarg <= -200.f) { h2s[KP(r)] = c0; }               // z==0 exactly
        else if (zarg >= 200.f && fabsf(wt) - fabsf(c0 * Uh) >= 30.f) {
          h2s[KP(r)] = copysignf(1.f, wt);                     // z==1, tanh saturated
        } else {
          atomicOr(&rbits[r >> 5], 1u << (r & 31)); atomicAdd(&s_nresc, 1);
        }
      }
    } else {
      for (int r = base; r < base + 8; ++r) atomicOr(&rbits[r >> 5], 1u << (r & 31));
      if (tid == 0) atomicAdd(&s_nresc, N_NODES);
    }
  }
  __syncthreads();
  if (s_nresc > 0) {   // cooperative exact rescue (never fires when certs hold)
    for (int w = 0; w < 256; ++w) {
      unsigned int bits = rbits[w];
      while (bits) {
        int b = __ffs(bits) - 1; bits &= bits - 1;
        int i = w * 32 + b;
        float acc = block_dot_8192(adj + (size_t)i * N_NODES, (const float4*)h1,
                                   wred, tid, wave, lane);
        if (tid == 0) {
          a2s[KP(i)] = acc;
          h2s[KP(i)] = gru_update(acc, h1[i], Wz, Uz, Wr, Ur, Wh, Uh);
        }
      }
    }
  }
  __syncthreads();

  // ================= phase B: GGNN step 3 =================
  if (tid == 0) { s_same = 1; s_eqc = 1; s_nresc = 0; }
  if (tid < 256) rbits[tid] = 0u;
  __syncthreads();
  const float c1 = h2s[KP(0)];
  {
    int same = 1, eqc = 1;
    for (int i = tid; i < N_NODES; i += 1024) {   // scalar: padded LDS + coalesced global
      float v = h2s[KP(i)];
      same &= (v == h1[i]) ? 1 : 0;
      eqc  &= (v == c1)    ? 1 : 0;
    }
    unsigned long long bs = __ballot(!same);
    unsigned long long be = __ballot(!eqc);
    if (lane == 0) {
      if (bs) atomicAnd(&s_same, 0);
      if (be) atomicAnd(&s_eqc, 0);
    }
  }
  __syncthreads();
  {
    const int fsame = s_same, feqc = s_eqc;
    if (fsame) {
      for (int r = base; r < base + 8; ++r) {
        float acc = a2s[KP(r)];
        keyz[KP(r)] = __float_as_uint(gru_update(acc, h2s[KP(r)], Wz, Uz, Wr, Ur, Wh, Uh));
      }
    } else if (feqc) {
      for (int r = base; r < base + 8; ++r) {
        float acc = c1 * rsum[r];
        float zarg = acc * Wz + c1 * Uz;
        float wt   = acc * Wh;
        if (zarg <= -200.f) { keyz[KP(r)] = __float_as_uint(c1); }
        else if (zarg >= 200.f && fabsf(wt) - fabsf(c1 * Uh) >= 30.f) {
          keyz[KP(r)] = __float_as_uint(copysignf(1.f, wt));
        } else {
          atomicOr(&rbits[r >> 5], 1u << (r & 31)); atomicAdd(&s_nresc, 1);
        }
      }
    } else {
      for (int r = base; r < base + 8; ++r) atomicOr(&rbits[r >> 5], 1u << (r & 31));
      if (tid == 0) atomicAdd(&s_nresc, N_NODES);
    }
  }
  __syncthreads();
  if (s_nresc > 0) {
    for (int w = 0; w < 256; ++w) {
      unsigned int bits = rbits[w];
      while (bits) {
        int b = __ffs(bits) - 1; bits &= bits - 1;
        int i = w * 32 + b;
        // h2 lives in padded LDS; rescue needs contiguous h2 vector -> rebuild via global a? 
        // Exact path: dot over padded LDS scalars (slow but never fires for certified data).
        float partial = 0.f;
        const float* arowp = adj + (size_t)i * N_NODES;
        for (int c = tid; c < N_NODES; c += 1024)
          partial = fmaf(arowp[c], h2s[KP(c)], partial);
        #pragma unroll
        for (int s = 32; s; s >>= 1) partial += __shfl_xor(partial, s);
        if (lane == 0) wred[wave] = partial;
        __syncthreads();
        if (tid == 0) {
          float t = 0.f;
          for (int w2 = 0; w2 < 16; ++w2) t += wred[w2];
          keyz[KP(i)] = __float_as_uint(gru_update(t, h2s[KP(i)], Wz, Uz, Wr, Ur, Wh, Uh));
        }
        __syncthreads();
      }
    }
  }
  __syncthreads();

  // ================= phase C: exact stable top-KEEP select =================
  for (int i = tid; i < N_NODES; i += 1024) {
    unsigned int u = keyz[KP(i)];
    keyz[KP(i)] = (u & 0x80000000u) ? ~u : (u | 0x80000000u);   // monotone f32->u32
  }
  if (tid == 0) { sh_prefix = 0u; sh_r = KEEP; }
  __syncthreads();

  for (int pass = 0; pass < 4; ++pass) {
    const int shift = 24 - pass * 8;
    if (tid < 256) hist[tid] = 0u;
    __syncthreads();
    const unsigned int pref = sh_prefix;
    const unsigned int r    = sh_r;
    #pragma unroll
    for (int i = 0; i < 8; ++i) {
      unsigned int k = keyz[KP(base + i)];
      bool match = (pass == 0) || ((k >> (shift + 8)) == pref);
      unsigned int d = match ? ((k >> shift) & 255u) : 256u;
      unsigned long long m = ~0ull;
      #pragma unroll
      for (int b = 0; b < 9; ++b) {
        unsigned long long bal = __ballot((d >> b) & 1u);
        m &= ((d >> b) & 1u) ? bal : ~bal;
      }
      int leader = __ffsll((unsigned long long)m) - 1;
      if (lane == leader && d < 256u)
        atomicAdd(&hist[d], (unsigned int)__popcll(m));
    }
    __syncthreads();
    if (wave == 0) {
      unsigned int t0 = hist[lane * 4], t1 = hist[lane * 4 + 1];
      unsigned int t2 = hist[lane * 4 + 2], t3 = hist[lane * 4 + 3];
      unsigned int tot = t0 + t1 + t2 + t3;
      unsigned int sc = tot;
      #pragma unroll
      for (int off = 1; off < 64; off <<= 1) {
        unsigned int o = __shfl_up(sc, off);
        if (lane >= off) sc += o;
      }
      unsigned int e = sc - tot;
      unsigned int p0 = e + t0, p1 = p0 + t1, p2 = p1 + t2, p3 = p2 + t3;
      if (r > e  && r <= p0) { sh_b = lane * 4;     sh_newr = r - e;  }
      if (r > p0 && r <= p1) { sh_b = lane * 4 + 1; sh_newr = r - p0; }
      if (r > p1 && r <= p2) { sh_b = lane * 4 + 2; sh_newr = r - p1; }
      if (r > p2 && r <= p3) { sh_b = lane * 4 + 3; sh_newr = r - p2; }
    }
    __syncthreads();
    if (tid == 0) { sh_prefix = (pref << 8) | sh_b; sh_r = sh_newr; }
    __syncthreads();
  }
  const unsigned int Kk = sh_prefix;
  const unsigned int tk = sh_r;

  unsigned int eqc = 0;
  #pragma unroll
  for (int i = 0; i < 8; ++i) eqc += (keyz[KP(base + i)] == Kk) ? 1u : 0u;
  const unsigned int eqbase = block_excl_scan_1024(eqc, wsum, wave, lane, tid);

  unsigned int runeq = eqbase, kc = 0;
  #pragma unroll
  for (int i = 0; i < 8; ++i) {
    unsigned int k = keyz[KP(base + i)];
    bool kp;
    if (k == Kk) { kp = (runeq < tk); ++runeq; } else kp = (k < Kk);
    kc += kp ? 1u : 0u;
  }
  unsigned int pos = block_excl_scan_1024(kc, wsum, wave, lane, tid);

  runeq = eqbase;
  #pragma unroll
  for (int i = 0; i < 8; ++i) {
    unsigned int k = keyz[KP(base + i)];
    bool kp;
    if (k == Kk) { kp = (runeq < tk); ++runeq; } else kp = (k < Kk);
    mask_out[base + i] = kp ? 1.0f : 0.0f;
    if (kp) keep_idx[pos++] = base + i;
  }
}

// ---------------- gather kept rows (float4: rows are 75 aligned float4) ----------------
__global__ __launch_bounds__(256) void gather_kernel(
    const float* __restrict__ He, const int* __restrict__ keep_idx,
    float* __restrict__ out) {
  int t = blockIdx.x * 256 + threadIdx.x;
  if (t >= KEEP * (HIDDEN / 4)) return;
  int p = t / (HIDDEN / 4);
  int c = t - p * (HIDDEN / 4);
  const float4* src = (const float4*)(He + (size_t)keep_idx[p] * HIDDEN);
  ((float4*)out)[t] = src[c];
}

extern "C" void kernel_launch(void* const* d_in, const int* in_sizes, int n_in,
                              void* d_out, int out_size, void* d_ws, size_t ws_size,
                              hipStream_t stream) {
  const float* He  = (const float*)d_in[0];
  const float* Hc  = (const float*)d_in[1];
  const float* adj = (const float*)d_in[2];
  const float* W1  = (const float*)d_in[3];
  const float* Wz  = (const float*)d_in[4];
  const float* Uz  = (const float*)d_in[5];
  const float* Wr  = (const float*)d_in[6];
  const float* Ur  = (const float*)d_in[7];
  const float* Wh  = (const float*)d_in[8];
  const float* Uh  = (const float*)d_in[9];
  float* out = (float*)d_out;

  float* ws   = (float*)d_ws;
  float* h0   = ws;                        // [8192]
  float* h1   = ws + 1 * N_NODES;
  float* a1   = ws + 2 * N_NODES;
  float* rsum = ws + 3 * N_NODES;
  int* keep_idx = (int*)(ws + 4 * N_NODES);

  float* mask_out = out + (size_t)KEEP * HIDDEN;

  score_prep_kernel  <<<N_NODES / 32, 512, 0, stream>>>(He, Hc, W1, h0);
  ggnn_step1         <<<N_NODES / 16, 1024, 0, stream>>>(adj, h0, h1, a1, rsum,
                                                         Wz, Uz, Wr, Ur, Wh, Uh);
  fused_refine_select<<<1, 1024, 0, stream>>>(h0, h1, a1, rsum, adj, mask_out, keep_idx,
                                              Wz, Uz, Wr, Ur, Wh, Uh);
  gather_kernel      <<<(KEEP * (HIDDEN / 4) + 255) / 256, 256, 0, stream>>>(He, keep_idx, out);
}